// Round 5
// baseline (1908.046 us; speedup 1.0000x reference)
//
#include <hip/hip_runtime.h>
#include <hip/hip_cooperative_groups.h>
#include <cstddef>

#define NN 50000
#define HH 128
#define TT 4
#define EE 150000

typedef __attribute__((ext_vector_type(8))) short bfrag8;
typedef __attribute__((ext_vector_type(4))) float f32x4;
typedef __attribute__((ext_vector_type(8))) unsigned short u16x8;

__device__ __forceinline__ float sigm(float v) { return 1.0f / (1.0f + __expf(-v)); }

__device__ __forceinline__ float gru_elem(float xr, float xz, float xn,
                                          float hr, float hz, float hn, float h) {
    float r = sigm(xr + hr);
    float z = sigm(xz + hz);
    float nn = tanhf(xn + r * hn);
    return (1.f - z) * nn + z * h;
}

__device__ __forceinline__ unsigned short f2b(float f) {
    unsigned int u = __float_as_uint(f);
    u += 0x7fffu + ((u >> 16) & 1u);
    return (unsigned short)(u >> 16);
}
__device__ __forceinline__ float b2f(unsigned short s) {
    return __uint_as_float(((unsigned int)s) << 16);
}

__device__ __forceinline__ void gload_lds16(const void* gp, void* lp) {
    __builtin_amdgcn_global_load_lds(
        (const __attribute__((address_space(1))) unsigned int*)gp,
        (__attribute__((address_space(3))) unsigned int*)lp, 16, 0, 0);
}

// ================= CSR build (once per call) =================
__global__ __launch_bounds__(256)
void deg2_kernel(const int* __restrict__ edges, int* __restrict__ deg) {
    int eg = blockIdx.x * 256 + threadIdx.x;
    if (eg >= TT * EE) return;
    atomicAdd(&deg[edges[eg * 2 + 1]], 1);
}

__global__ __launch_bounds__(256)
void scan_block(const int* __restrict__ d, int* __restrict__ loc,
                int* __restrict__ bsum, int n) {
    __shared__ int sh[256];
    const int tid = threadIdx.x;
    const int i = blockIdx.x * 256 + tid;
    int v = (i < n) ? d[i] : 0;
    sh[tid] = v;
    __syncthreads();
    #pragma unroll
    for (int off = 1; off < 256; off <<= 1) {
        int t = (tid >= off) ? sh[tid - off] : 0;
        __syncthreads();
        sh[tid] += t;
        __syncthreads();
    }
    if (i < n) loc[i] = sh[tid];
    if (tid == 255) bsum[blockIdx.x] = sh[255];
}

__global__ __launch_bounds__(1024)
void scan_partials(const int* __restrict__ bsum, int* __restrict__ bpref, int nblk) {
    __shared__ int sh[1024];
    const int tid = threadIdx.x;
    sh[tid] = (tid < nblk) ? bsum[tid] : 0;
    __syncthreads();
    #pragma unroll
    for (int off = 1; off < 1024; off <<= 1) {
        int t = (tid >= off) ? sh[tid - off] : 0;
        __syncthreads();
        sh[tid] += t;
        __syncthreads();
    }
    if (tid < nblk) bpref[tid] = (tid == 0) ? 0 : sh[tid - 1];
}

__global__ __launch_bounds__(256)
void fill_base(const int* __restrict__ d, const int* __restrict__ loc,
               const int* __restrict__ bpref, int* __restrict__ base,
               int* __restrict__ cursor, int n) {
    const int i = blockIdx.x * 256 + threadIdx.x;
    if (i >= n) return;
    const int incl = loc[i] + bpref[blockIdx.x];
    base[i] = incl - d[i];
    cursor[i] = 0;
    if (i == n - 1) base[n] = incl;
}

__global__ __launch_bounds__(256)
void place2_kernel(const int* __restrict__ edges, const int* __restrict__ base,
                   int* __restrict__ cursor, unsigned int* __restrict__ rows) {
    int eg = blockIdx.x * 256 + threadIdx.x;
    if (eg >= TT * EE) return;
    int t = eg / EE;
    int src = edges[eg * 2];
    int tgt = edges[eg * 2 + 1];
    int p = base[tgt] + atomicAdd(&cursor[tgt], 1);
    rows[p] = (unsigned int)src * 512u + (unsigned int)t * 128u;
}

// ================= fused setup converts (one kernel) =================
// permuted row: f(0..383) -> rp = ((f&127)>>4)*48 + (f>>7)*16 + (f&15)
__device__ __forceinline__ int permrow(int f) {
    int gc = f & 127, ch = f >> 7;
    return (gc >> 4) * 48 + ch * 16 + (gc & 15);
}

__global__ __launch_bounds__(256)
void setup_convert(const float* __restrict__ msg_W,
                   const float* __restrict__ W0ih, const float* __restrict__ W0hh,
                   const float* __restrict__ W1ih, const float* __restrict__ W1hh,
                   const float* __restrict__ b0ih, const float* __restrict__ b0hh,
                   const float* __restrict__ b1ih, const float* __restrict__ b1hh,
                   const float* __restrict__ x,
                   unsigned short* __restrict__ msgWb,
                   unsigned short* __restrict__ W0ihP, unsigned short* __restrict__ W0hhP,
                   unsigned short* __restrict__ W1ihP, unsigned short* __restrict__ W1hhP,
                   float* __restrict__ biasP,
                   unsigned short* __restrict__ xb, unsigned short* __restrict__ hbA,
                   float* __restrict__ out) {
    int i = blockIdx.x * 256 + threadIdx.x;
    if (i < 131072) { msgWb[i] = f2b(msg_W[i]); return; }
    i -= 131072;
    if (i < 49152) { int f = i >> 7, k = i & 127; W0ihP[permrow(f) * 128 + k] = f2b(W0ih[i]); return; }
    i -= 49152;
    if (i < 49152) { int f = i >> 7, k = i & 127; W0hhP[permrow(f) * 128 + k] = f2b(W0hh[i]); return; }
    i -= 49152;
    if (i < 98304) { int f = i >> 8, k = i & 255; W1ihP[permrow(f) * 256 + k] = f2b(W1ih[i]); return; }
    i -= 98304;
    if (i < 49152) { int f = i >> 7, k = i & 127; W1hhP[permrow(f) * 128 + k] = f2b(W1hh[i]); return; }
    i -= 49152;
    if (i < 1536) {
        int which = i / 384, f = i - which * 384;
        const float* src = (which == 0) ? b0ih : (which == 1) ? b0hh : (which == 2) ? b1ih : b1hh;
        biasP[which * 384 + permrow(f)] = src[f];
        return;
    }
    i -= 1536;
    if (i < NN * HH) {
        float v = x[i];
        unsigned short b = f2b(v);
        xb[i] = b;
        hbA[i] = b;
        out[i] = v;
    }
}

// ================= tile routines for the cooperative kernel =================
// LDS panel convention (per 64x64-elem k-panel of bf16): LDS[r][slot(0..7)]
// holds the 8-elem chunk (slot ^ (r&7)) of row r  — global_load_lds-compatible
// swizzle, conflict-free ds_read_b128 (m97 pattern, proven R3/R4).

__device__ __forceinline__ void z_tile(
    int tile, const unsigned short* __restrict__ hb,
    const unsigned short* __restrict__ Wm, const float* __restrict__ bm,
    unsigned short* __restrict__ Zb, unsigned short* lds) {
    const int tid = threadIdx.x;
    const int lane = tid & 63;
    const int w = tid >> 6;
    const int ln15 = lane & 15;
    const int quad = lane >> 4;
    const int swz = ln15 & 7;
    const int mbase = tile * 64;
    #pragma unroll
    for (int j = 0; j < 4; ++j) {
        const int idx = w * 4 + j;          // 16 wave-loads cover 2 panels
        const int kt = idx >> 3, ib = idx & 7;
        const int r = ib * 8 + (lane >> 3);
        int grow = mbase + r; if (grow > NN - 1) grow = NN - 1;
        gload_lds16(hb + (size_t)grow * 128 + kt * 64 + (((lane & 7) ^ (lane >> 3)) << 3),
                    &lds[kt * 4096 + ib * 512]);
    }
    __syncthreads();
    f32x4 acc[4][8];
    #pragma unroll
    for (int mt = 0; mt < 4; ++mt)
        #pragma unroll
        for (int nt = 0; nt < 8; ++nt) acc[mt][nt] = (f32x4){0.f, 0.f, 0.f, 0.f};
    #pragma unroll
    for (int kt = 0; kt < 2; ++kt) {
        #pragma unroll
        for (int kk = 0; kk < 2; ++kk) {
            bfrag8 aF[4], bF[8];
            #pragma unroll
            for (int mt = 0; mt < 4; ++mt)
                aF[mt] = *(const bfrag8*)&lds[kt * 4096 + (mt * 16 + ln15) * 64 +
                                              (((kk * 4 + quad) ^ swz) << 3)];
            #pragma unroll
            for (int nt = 0; nt < 8; ++nt)
                bF[nt] = *(const bfrag8*)&Wm[(size_t)(w * 128 + nt * 16 + ln15) * 128 +
                                             kt * 64 + kk * 32 + quad * 8];
            #pragma unroll
            for (int mt = 0; mt < 4; ++mt)
                #pragma unroll
                for (int nt = 0; nt < 8; ++nt)
                    acc[mt][nt] = __builtin_amdgcn_mfma_f32_16x16x32_bf16(
                        aF[mt], bF[nt], acc[mt][nt], 0, 0, 0);
        }
    }
    __syncthreads();   // LDS free for next tile's staging
    float bcol[8];
    #pragma unroll
    for (int nt = 0; nt < 8; ++nt) bcol[nt] = bm[w * 128 + nt * 16 + ln15];
    #pragma unroll
    for (int mt = 0; mt < 4; ++mt)
        #pragma unroll
        for (int reg = 0; reg < 4; ++reg) {
            const int row = mbase + mt * 16 + quad * 4 + reg;
            if (row < NN) {
                #pragma unroll
                for (int nt = 0; nt < 8; ++nt)
                    Zb[(size_t)row * 512 + w * 128 + nt * 16 + ln15] =
                        f2b(acc[mt][nt][reg] + bcol[nt]);
            }
        }
}

__device__ __forceinline__ void mega_tile(
    int tile, int l, const unsigned short* __restrict__ hb,
    const unsigned short* __restrict__ xb,
    const int* __restrict__ base2, const unsigned int* __restrict__ rows,
    const unsigned short* __restrict__ Zb,
    const unsigned short* __restrict__ WihP, int K, const float* __restrict__ bih,
    const unsigned short* __restrict__ WhhP, const float* __restrict__ bhh,
    const float* __restrict__ hcur, float* __restrict__ hnext,
    unsigned short* __restrict__ hbn, unsigned short* lds) {
    const int tid = threadIdx.x;
    const int lane = tid & 63;
    const int w = tid >> 6;
    const int ln15 = lane & 15;
    const int quad = lane >> 4;
    const int swz = ln15 & 7;
    const int mbase = tile * 64;

    // stage hb panels [0..8192) and (l==1) xb panels [16384..24576)
    #pragma unroll
    for (int j = 0; j < 4; ++j) {
        const int idx = w * 4 + j;
        const int kt = idx >> 3, ib = idx & 7;
        const int r = ib * 8 + (lane >> 3);
        int grow = mbase + r; if (grow > NN - 1) grow = NN - 1;
        const int slot = ((lane & 7) ^ (lane >> 3)) << 3;
        gload_lds16(hb + (size_t)grow * 128 + kt * 64 + slot, &lds[kt * 4096 + ib * 512]);
        if (l == 1)
            gload_lds16(xb + (size_t)grow * 128 + kt * 64 + slot,
                        &lds[16384 + kt * 4096 + ib * 512]);
    }
    // gather inc into [8192..16384), swizzled A-panel layout
    {
        const int c8 = tid & 15;
        #pragma unroll
        for (int pass = 0; pass < 4; ++pass) {
            const int r = pass * 16 + (tid >> 4);
            int n = mbase + r; if (n > NN - 1) n = NN - 1;
            const int p0 = base2[n], p1 = base2[n + 1];
            float a[8] = {};
            int pp = p0;
            for (; pp + 4 <= p1; pp += 4) {
                const unsigned int o0 = rows[pp], o1 = rows[pp + 1];
                const unsigned int o2 = rows[pp + 2], o3 = rows[pp + 3];
                const u16x8 v0 = *(const u16x8*)&Zb[o0 + c8 * 8];
                const u16x8 v1 = *(const u16x8*)&Zb[o1 + c8 * 8];
                const u16x8 v2 = *(const u16x8*)&Zb[o2 + c8 * 8];
                const u16x8 v3 = *(const u16x8*)&Zb[o3 + c8 * 8];
                #pragma unroll
                for (int jj = 0; jj < 8; ++jj)
                    a[jj] += (b2f((unsigned short)v0[jj]) + b2f((unsigned short)v1[jj]))
                           + (b2f((unsigned short)v2[jj]) + b2f((unsigned short)v3[jj]));
            }
            for (; pp < p1; ++pp) {
                const u16x8 v = *(const u16x8*)&Zb[rows[pp] + c8 * 8];
                #pragma unroll
                for (int jj = 0; jj < 8; ++jj) a[jj] += b2f((unsigned short)v[jj]);
            }
            u16x8 o;
            #pragma unroll
            for (int jj = 0; jj < 8; ++jj) o[jj] = f2b(a[jj]);
            const int panel = c8 >> 3, cc = c8 & 7;
            *(u16x8*)&lds[8192 + panel * 4096 + r * 64 + ((cc ^ (r & 7)) << 3)] = o;
        }
    }
    __syncthreads();

    // ---- gx GEMM: wave w covers permuted cols w*96..+96 ----
    f32x4 acc[4][6];
    #pragma unroll
    for (int mt = 0; mt < 4; ++mt)
        #pragma unroll
        for (int nt = 0; nt < 6; ++nt) acc[mt][nt] = (f32x4){0.f, 0.f, 0.f, 0.f};
    const int nkt = (l == 1) ? 4 : 2;
    for (int kt = 0; kt < nkt; ++kt) {
        const unsigned short* ldsA = (l == 1)
            ? ((kt < 2) ? &lds[16384 + kt * 4096] : &lds[8192 + (kt - 2) * 4096])
            : &lds[8192 + kt * 4096];
        #pragma unroll
        for (int kk = 0; kk < 2; ++kk) {
            bfrag8 aF[4], bF[6];
            #pragma unroll
            for (int mt = 0; mt < 4; ++mt)
                aF[mt] = *(const bfrag8*)&ldsA[(mt * 16 + ln15) * 64 +
                                               (((kk * 4 + quad) ^ swz) << 3)];
            #pragma unroll
            for (int nt = 0; nt < 6; ++nt)
                bF[nt] = *(const bfrag8*)&WihP[(size_t)(w * 96 + nt * 16 + ln15) * K +
                                               kt * 64 + kk * 32 + quad * 8];
            #pragma unroll
            for (int mt = 0; mt < 4; ++mt)
                #pragma unroll
                for (int nt = 0; nt < 6; ++nt)
                    acc[mt][nt] = __builtin_amdgcn_mfma_f32_16x16x32_bf16(
                        aF[mt], bF[nt], acc[mt][nt], 0, 0, 0);
        }
    }
    // bias + pack gx to bf16 pairs (frees acc for gh)
    unsigned int gxp[4][6][2];
    #pragma unroll
    for (int nt = 0; nt < 6; ++nt) {
        const float bi = bih[w * 96 + nt * 16 + ln15];
        #pragma unroll
        for (int mt = 0; mt < 4; ++mt) {
            const float v0 = acc[mt][nt][0] + bi, v1 = acc[mt][nt][1] + bi;
            const float v2 = acc[mt][nt][2] + bi, v3 = acc[mt][nt][3] + bi;
            gxp[mt][nt][0] = ((unsigned int)f2b(v1) << 16) | f2b(v0);
            gxp[mt][nt][1] = ((unsigned int)f2b(v3) << 16) | f2b(v2);
        }
    }
    // ---- gh GEMM (reuse acc) ----
    #pragma unroll
    for (int mt = 0; mt < 4; ++mt)
        #pragma unroll
        for (int nt = 0; nt < 6; ++nt) acc[mt][nt] = (f32x4){0.f, 0.f, 0.f, 0.f};
    #pragma unroll
    for (int kt = 0; kt < 2; ++kt) {
        #pragma unroll
        for (int kk = 0; kk < 2; ++kk) {
            bfrag8 aF[4], bF[6];
            #pragma unroll
            for (int mt = 0; mt < 4; ++mt)
                aF[mt] = *(const bfrag8*)&lds[kt * 4096 + (mt * 16 + ln15) * 64 +
                                              (((kk * 4 + quad) ^ swz) << 3)];
            #pragma unroll
            for (int nt = 0; nt < 6; ++nt)
                bF[nt] = *(const bfrag8*)&WhhP[(size_t)(w * 96 + nt * 16 + ln15) * 128 +
                                               kt * 64 + kk * 32 + quad * 8];
            #pragma unroll
            for (int mt = 0; mt < 4; ++mt)
                #pragma unroll
                for (int nt = 0; nt < 6; ++nt)
                    acc[mt][nt] = __builtin_amdgcn_mfma_f32_16x16x32_bf16(
                        aF[mt], bF[nt], acc[mt][nt], 0, 0, 0);
        }
    }
    __syncthreads();   // LDS free for next tile

    // ---- GRU gate epilogue (wave-local: r/z/n of a gate col live in same lane) ----
    #pragma unroll
    for (int g = 0; g < 2; ++g) {
        const int grp = w * 2 + g;
        const float br = bhh[grp * 48 + ln15];
        const float bz = bhh[grp * 48 + 16 + ln15];
        const float bn = bhh[grp * 48 + 32 + ln15];
        const int col = grp * 16 + ln15;
        #pragma unroll
        for (int mt = 0; mt < 4; ++mt)
            #pragma unroll
            for (int reg = 0; reg < 4; ++reg) {
                const int row = mbase + mt * 16 + quad * 4 + reg;
                if (row < NN) {
                    const int hw = reg >> 1, sh = (reg & 1) * 16;
                    const float xr = b2f((unsigned short)(gxp[mt][g * 3 + 0][hw] >> sh));
                    const float xz = b2f((unsigned short)(gxp[mt][g * 3 + 1][hw] >> sh));
                    const float xn = b2f((unsigned short)(gxp[mt][g * 3 + 2][hw] >> sh));
                    const float hr = acc[mt][g * 3 + 0][reg] + br;
                    const float hz = acc[mt][g * 3 + 1][reg] + bz;
                    const float hn = acc[mt][g * 3 + 2][reg] + bn;
                    const float h = hcur[(size_t)row * 128 + col];
                    const float o = gru_elem(xr, xz, xn, hr, hz, hn, h);
                    hnext[(size_t)row * 128 + col] = o;
                    hbn[(size_t)row * 128 + col] = f2b(o);
                }
            }
    }
}

// ================= the cooperative 6-step kernel =================
struct P {
    const int* base2; const unsigned int* rows;
    unsigned short* Zb; unsigned short* hbA; unsigned short* hbB;
    const unsigned short* xb;
    const unsigned short* msgWb; const float* msg_b;
    const unsigned short* W0ihP; const unsigned short* W0hhP;
    const unsigned short* W1ihP; const unsigned short* W1hhP;
    const float* biasP; float* hA; float* out; int* ctrs;
};

#define NTILES 782   // ceil(NN/64)

__global__ __launch_bounds__(256, 2)
void fused6(P p) {
    cooperative_groups::grid_group gg = cooperative_groups::this_grid();
    __shared__ unsigned short lds[24576];   // 48 KB
    __shared__ int s_t;
    for (int s = 0; s < 6; ++s) {
        const int l = s / 3;
        const unsigned short* hbc = (s & 1) ? p.hbB : p.hbA;
        unsigned short* hbn = (s & 1) ? p.hbA : p.hbB;
        const float* hcur = (s & 1) ? p.hA : p.out;
        float* hnext = (s & 1) ? p.out : p.hA;
        const unsigned short* Wm = p.msgWb + l * 65536;
        const float* bm = p.msg_b + l * 512;
        // phase Z (atomic tile queue for CU-level balance)
        while (true) {
            if (threadIdx.x == 0) s_t = atomicAdd(&p.ctrs[2 * s], 1);
            __syncthreads();
            const int t = s_t;
            if (t >= NTILES) break;
            z_tile(t, hbc, Wm, bm, p.Zb, lds);
        }
        gg.sync();
        // phase mega: gather + gx-GEMM + gh-GEMM + gate
        const unsigned short* WihP = l ? p.W1ihP : p.W0ihP;
        const unsigned short* WhhP = l ? p.W1hhP : p.W0hhP;
        const float* bih = p.biasP + (l ? 768 : 0);
        const float* bhh = p.biasP + (l ? 1152 : 384);
        const int K = l ? 256 : 128;
        while (true) {
            if (threadIdx.x == 0) s_t = atomicAdd(&p.ctrs[2 * s + 1], 1);
            __syncthreads();
            const int t = s_t;
            if (t >= NTILES) break;
            mega_tile(t, l, hbc, p.xb, p.base2, p.rows, p.Zb, WihP, K, bih,
                      WhhP, bhh, hcur, hnext, hbn, lds);
        }
        gg.sync();
    }
}

extern "C" void kernel_launch(void* const* d_in, const int* in_sizes, int n_in,
                              void* d_out, int out_size, void* d_ws, size_t ws_size,
                              hipStream_t stream) {
    (void)in_sizes; (void)n_in; (void)out_size; (void)ws_size;
    const float* x     = (const float*)d_in[0];
    const int*   edges = (const int*)d_in[1];
    const float* msg_W = (const float*)d_in[2];
    const float* msg_b = (const float*)d_in[3];
    const float* W0ih  = (const float*)d_in[4];
    const float* W0hh  = (const float*)d_in[5];
    const float* b0ih  = (const float*)d_in[6];
    const float* b0hh  = (const float*)d_in[7];
    const float* W1ih  = (const float*)d_in[8];
    const float* W1hh  = (const float*)d_in[9];
    const float* b1ih  = (const float*)d_in[10];
    const float* b1hh  = (const float*)d_in[11];
    float* out = (float*)d_out;

    // ---- workspace layout (float units) ----
    float* ws = (float*)d_ws;
    unsigned short* Zb  = (unsigned short*)ws;                   // N*512 u16 = 12.8M fl
    unsigned short* xb  = (unsigned short*)(ws + 12800000);      // N*128 u16
    unsigned short* hbA = (unsigned short*)(ws + 16000000);
    unsigned short* hbB = (unsigned short*)(ws + 19200000);
    float* hA           = ws + 22400000;                         // N*128 fp32
    unsigned short* wb  = (unsigned short*)(ws + 28800000);
    unsigned short* msgWb = wb;               // 131072 u16
    unsigned short* W0ihP = wb + 131072;      // 49152
    unsigned short* W0hhP = wb + 180224;      // 49152
    unsigned short* W1ihP = wb + 229376;      // 98304
    unsigned short* W1hhP = wb + 327680;      // 49152
    float* biasP        = ws + 29000000;                         // 1536 fl
    int*          base2 = (int*)(ws + 29010000);                 // NN+1
    unsigned int* rows  = (unsigned int*)(ws + 29070000);        // T*E
    int*          ctrs  = (int*)(ws + 29700000);                 // 16 ints
    // build temporaries alias Zb region (dead before fused6 writes Zb)
    int* deg2      = (int*)ws;
    int* locscan   = deg2 + NN;
    int* cursor    = deg2 + 2 * NN;
    int* blocksum  = deg2 + 3 * NN;
    int* blockpref = deg2 + 3 * NN + 1024;

    // ---- CSR build ----
    const int nblk2 = (NN + 255) / 256;  // 196
    hipMemsetAsync(deg2, 0, (size_t)NN * sizeof(int), stream);
    hipMemsetAsync(ctrs, 0, 16 * sizeof(int), stream);
    deg2_kernel<<<(TT * EE + 255) / 256, 256, 0, stream>>>(edges, deg2);
    scan_block<<<nblk2, 256, 0, stream>>>(deg2, locscan, blocksum, NN);
    scan_partials<<<1, 1024, 0, stream>>>(blocksum, blockpref, nblk2);
    fill_base<<<nblk2, 256, 0, stream>>>(deg2, locscan, blockpref, base2, cursor, NN);
    place2_kernel<<<(TT * EE + 255) / 256, 256, 0, stream>>>(edges, base2, cursor, rows);

    // ---- fused converts (writes out = x too) ----
    setup_convert<<<26478, 256, 0, stream>>>(msg_W, W0ih, W0hh, W1ih, W1hh,
                                             b0ih, b0hh, b1ih, b1hh, x,
                                             msgWb, W0ihP, W0hhP, W1ihP, W1hhP,
                                             biasP, xb, hbA, out);

    // ---- cooperative 6-step kernel ----
    P prm;
    prm.base2 = base2; prm.rows = rows; prm.Zb = Zb;
    prm.hbA = hbA; prm.hbB = hbB; prm.xb = xb;
    prm.msgWb = msgWb; prm.msg_b = msg_b;
    prm.W0ihP = W0ihP; prm.W0hhP = W0hhP; prm.W1ihP = W1ihP; prm.W1hhP = W1hhP;
    prm.biasP = biasP; prm.hA = hA; prm.out = out; prm.ctrs = ctrs;
    void* kargs[] = {&prm};
    int nb = 2;
    hipOccupancyMaxActiveBlocksPerMultiprocessor(&nb, fused6, 256, 0);
    if (nb < 1) nb = 1;
    int grid = nb * 256;
    if (grid > 512) grid = 512;
    hipLaunchCooperativeKernel((void*)fused6, dim3(grid), dim3(256), kargs, 0, stream);
}

// Round 6
// 947.112 us; speedup vs baseline: 2.0146x; 2.0146x over previous
//
#include <hip/hip_runtime.h>
#include <cstddef>

#define NN 50000
#define HH 128
#define TT 4
#define EE 150000

typedef __attribute__((ext_vector_type(8))) short bfrag8;
typedef __attribute__((ext_vector_type(4))) float f32x4;
typedef __attribute__((ext_vector_type(8))) unsigned short u16x8;

__device__ __forceinline__ float sigm(float v) { return 1.0f / (1.0f + __expf(-v)); }

__device__ __forceinline__ float gru_elem(float xr, float xz, float xn,
                                          float hr, float hz, float hn, float h) {
    float r = sigm(xr + hr);
    float z = sigm(xz + hz);
    float nn = tanhf(xn + r * hn);
    return (1.f - z) * nn + z * h;
}

__device__ __forceinline__ unsigned short f2b(float f) {
    unsigned int u = __float_as_uint(f);
    u += 0x7fffu + ((u >> 16) & 1u);
    return (unsigned short)(u >> 16);
}
__device__ __forceinline__ float b2f(unsigned short s) {
    return __uint_as_float(((unsigned int)s) << 16);
}

__device__ __forceinline__ void gload_lds16(const void* gp, void* lp) {
    __builtin_amdgcn_global_load_lds(
        (const __attribute__((address_space(1))) unsigned int*)gp,
        (__attribute__((address_space(3))) unsigned int*)lp, 16, 0, 0);
}

// ================= CSR build (once per call) =================
__global__ __launch_bounds__(256)
void deg2_kernel(const int* __restrict__ edges, int* __restrict__ deg) {
    int eg = blockIdx.x * 256 + threadIdx.x;
    if (eg >= TT * EE) return;
    atomicAdd(&deg[edges[eg * 2 + 1]], 1);
}

__global__ __launch_bounds__(256)
void scan_block(const int* __restrict__ d, int* __restrict__ loc,
                int* __restrict__ bsum, int n) {
    __shared__ int sh[256];
    const int tid = threadIdx.x;
    const int i = blockIdx.x * 256 + tid;
    int v = (i < n) ? d[i] : 0;
    sh[tid] = v;
    __syncthreads();
    #pragma unroll
    for (int off = 1; off < 256; off <<= 1) {
        int t = (tid >= off) ? sh[tid - off] : 0;
        __syncthreads();
        sh[tid] += t;
        __syncthreads();
    }
    if (i < n) loc[i] = sh[tid];
    if (tid == 255) bsum[blockIdx.x] = sh[255];
}

__global__ __launch_bounds__(1024)
void scan_partials(const int* __restrict__ bsum, int* __restrict__ bpref, int nblk) {
    __shared__ int sh[1024];
    const int tid = threadIdx.x;
    sh[tid] = (tid < nblk) ? bsum[tid] : 0;
    __syncthreads();
    #pragma unroll
    for (int off = 1; off < 1024; off <<= 1) {
        int t = (tid >= off) ? sh[tid - off] : 0;
        __syncthreads();
        sh[tid] += t;
        __syncthreads();
    }
    if (tid < nblk) bpref[tid] = (tid == 0) ? 0 : sh[tid - 1];
}

__global__ __launch_bounds__(256)
void fill_base(const int* __restrict__ d, const int* __restrict__ loc,
               const int* __restrict__ bpref, int* __restrict__ base,
               int* __restrict__ cursor, int n) {
    const int i = blockIdx.x * 256 + threadIdx.x;
    if (i >= n) return;
    const int incl = loc[i] + bpref[blockIdx.x];
    base[i] = incl - d[i];
    cursor[i] = 0;
    if (i == n - 1) base[n] = incl;
}

__global__ __launch_bounds__(256)
void place2_kernel(const int* __restrict__ edges, const int* __restrict__ base,
                   int* __restrict__ cursor, unsigned int* __restrict__ rows) {
    int eg = blockIdx.x * 256 + threadIdx.x;
    if (eg >= TT * EE) return;
    int t = eg / EE;
    int src = edges[eg * 2];
    int tgt = edges[eg * 2 + 1];
    int p = base[tgt] + atomicAdd(&cursor[tgt], 1);
    rows[p] = (unsigned int)src * 512u + (unsigned int)t * 128u;
}

// ================= fused setup converts =================
__device__ __forceinline__ int permrow(int f) {
    int gc = f & 127, ch = f >> 7;
    return (gc >> 4) * 48 + ch * 16 + (gc & 15);
}

__global__ __launch_bounds__(256)
void setup_convert(const float* __restrict__ msg_W,
                   const float* __restrict__ W0ih, const float* __restrict__ W0hh,
                   const float* __restrict__ W1ih, const float* __restrict__ W1hh,
                   const float* __restrict__ b0ih, const float* __restrict__ b0hh,
                   const float* __restrict__ b1ih, const float* __restrict__ b1hh,
                   const float* __restrict__ x,
                   unsigned short* __restrict__ msgWb,
                   unsigned short* __restrict__ W0ihP, unsigned short* __restrict__ W0hhP,
                   unsigned short* __restrict__ W1ihP, unsigned short* __restrict__ W1hhP,
                   float* __restrict__ biasP,
                   unsigned short* __restrict__ xb, unsigned short* __restrict__ hbA,
                   float* __restrict__ out) {
    int i = blockIdx.x * 256 + threadIdx.x;
    if (i < 131072) { msgWb[i] = f2b(msg_W[i]); return; }
    i -= 131072;
    if (i < 49152) { int f = i >> 7, k = i & 127; W0ihP[permrow(f) * 128 + k] = f2b(W0ih[i]); return; }
    i -= 49152;
    if (i < 49152) { int f = i >> 7, k = i & 127; W0hhP[permrow(f) * 128 + k] = f2b(W0hh[i]); return; }
    i -= 49152;
    if (i < 98304) { int f = i >> 8, k = i & 255; W1ihP[permrow(f) * 256 + k] = f2b(W1ih[i]); return; }
    i -= 98304;
    if (i < 49152) { int f = i >> 7, k = i & 127; W1hhP[permrow(f) * 128 + k] = f2b(W1hh[i]); return; }
    i -= 49152;
    if (i < 1536) {
        int which = i / 384, f = i - which * 384;
        const float* src = (which == 0) ? b0ih : (which == 1) ? b0hh : (which == 2) ? b1ih : b1hh;
        biasP[which * 384 + permrow(f)] = src[f];
        return;
    }
    i -= 1536;
    if (i < NN * HH) {
        float v = x[i];
        unsigned short b = f2b(v);
        xb[i] = b;
        hbA[i] = b;
        out[i] = v;
    }
}

// ================= gather: inc[n] = sum_edges Z[rows[p] + c] =================
__global__ __launch_bounds__(256)
void gather2(const int* __restrict__ base, const unsigned int* __restrict__ rows,
             const unsigned short* __restrict__ Z, unsigned short* __restrict__ incb) {
    int gid = blockIdx.x * 256 + threadIdx.x;
    int n = gid >> 4;
    int c = (gid & 15) * 8;
    const int p0 = base[n];
    const int p1 = base[n + 1];
    float a[8] = {};
    int p = p0;
    for (; p + 4 <= p1; p += 4) {
        unsigned int o0 = rows[p], o1 = rows[p + 1], o2 = rows[p + 2], o3 = rows[p + 3];
        u16x8 v0 = *(const u16x8*)&Z[o0 + c];
        u16x8 v1 = *(const u16x8*)&Z[o1 + c];
        u16x8 v2 = *(const u16x8*)&Z[o2 + c];
        u16x8 v3 = *(const u16x8*)&Z[o3 + c];
        #pragma unroll
        for (int j = 0; j < 8; ++j)
            a[j] += (b2f((unsigned short)v0[j]) + b2f((unsigned short)v1[j]))
                  + (b2f((unsigned short)v2[j]) + b2f((unsigned short)v3[j]));
    }
    for (; p < p1; ++p) {
        u16x8 v = *(const u16x8*)&Z[rows[p] + c];
        #pragma unroll
        for (int j = 0; j < 8; ++j) a[j] += b2f((unsigned short)v[j]);
    }
    u16x8 o;
    #pragma unroll
    for (int j = 0; j < 8; ++j) o[j] = f2b(a[j]);
    *(u16x8*)&incb[(size_t)n * 128 + c] = o;
}

// ================= Z GEMM: Z = h @ msgW^T + msg_b (128x128 tile) =================
__global__ __launch_bounds__(256)
void z_gemm(const unsigned short* __restrict__ A0,
            const unsigned short* __restrict__ B,
            const float* __restrict__ bias,
            unsigned short* __restrict__ C) {
    __shared__ unsigned short lsA[128 * 64];
    __shared__ unsigned short lsB[128 * 64];
    const int tid = threadIdx.x;
    const int lane = tid & 63;
    const int w = tid >> 6;
    const int wm = w >> 1, wn = w & 1;
    const int ln15 = lane & 15;
    const int quad = lane >> 4;
    const int swz = ln15 & 7;
    const int mbase = blockIdx.x * 128;
    const int fbase = blockIdx.y * 128;
    const int qg = (lane & 7) ^ (lane >> 3);

    f32x4 acc[4][4];
    #pragma unroll
    for (int i = 0; i < 4; ++i)
        #pragma unroll
        for (int j = 0; j < 4; ++j)
            acc[i][j] = (f32x4){0.f, 0.f, 0.f, 0.f};

    #pragma unroll
    for (int tile = 0; tile < 2; ++tile) {
        const int ck0 = tile << 3;
        #pragma unroll
        for (int i = 0; i < 4; ++i) {
            const int r = i * 32 + (w << 3) + (lane >> 3);
            const int chunk = ck0 + qg;
            int grow = mbase + r;
            if (grow > NN - 1) grow = NN - 1;
            const int kel = chunk << 3;
            gload_lds16(A0 + (size_t)grow * 128 + kel, &lsA[(i * 32 + (w << 3)) * 64]);
            gload_lds16(B + (size_t)(fbase + r) * 128 + kel, &lsB[(i * 32 + (w << 3)) * 64]);
        }
        __syncthreads();
        #pragma unroll
        for (int kk = 0; kk < 2; ++kk) {
            const int cs = (((kk * 4 + quad) ^ swz)) << 3;
            bfrag8 aF[4], bF[4];
            #pragma unroll
            for (int mt = 0; mt < 4; ++mt)
                aF[mt] = *(const bfrag8*)&lsA[(wm * 64 + mt * 16 + ln15) * 64 + cs];
            #pragma unroll
            for (int nt = 0; nt < 4; ++nt)
                bF[nt] = *(const bfrag8*)&lsB[(wn * 64 + nt * 16 + ln15) * 64 + cs];
            #pragma unroll
            for (int mt = 0; mt < 4; ++mt)
                #pragma unroll
                for (int nt = 0; nt < 4; ++nt)
                    acc[mt][nt] = __builtin_amdgcn_mfma_f32_16x16x32_bf16(
                        aF[mt], bF[nt], acc[mt][nt], 0, 0, 0);
        }
        __syncthreads();
    }

    float bcol[4];
    #pragma unroll
    for (int nt = 0; nt < 4; ++nt)
        bcol[nt] = bias[fbase + wn * 64 + nt * 16 + ln15];
    #pragma unroll
    for (int mt = 0; mt < 4; ++mt) {
        #pragma unroll
        for (int reg = 0; reg < 4; ++reg) {
            const int grow = mbase + wm * 64 + mt * 16 + quad * 4 + reg;
            if (grow < NN) {
                #pragma unroll
                for (int nt = 0; nt < 4; ++nt) {
                    const int gcol = fbase + wn * 64 + nt * 16 + ln15;
                    C[(size_t)grow * 512 + gcol] = f2b(acc[mt][nt][reg] + bcol[nt]);
                }
            }
        }
    }
}

// ================= fused gx-GEMM + gh-GEMM + GRU gate =================
// M-tile 64, 256 threads (4 waves); wave w covers permuted cols w*96..+96 of 384.
// A panels in LDS (h always; inc; x for L=1); B weights global-direct (L2-hot).
// gx kept in registers (bf16 packed), gates applied in epilogue.
template<int L>
__global__ __launch_bounds__(256)
void gxhgate(const unsigned short* __restrict__ hb,
             const unsigned short* __restrict__ xb,
             const unsigned short* __restrict__ incb,
             const unsigned short* __restrict__ WihP, const float* __restrict__ bih,
             const unsigned short* __restrict__ WhhP, const float* __restrict__ bhh,
             const float* __restrict__ hcur,
             float* __restrict__ hnext, unsigned short* __restrict__ hbn) {
    __shared__ unsigned short lds[L ? 24576 : 16384];   // h | (x) | inc panels
    const int tid = threadIdx.x;
    const int lane = tid & 63;
    const int w = tid >> 6;
    const int ln15 = lane & 15;
    const int quad = lane >> 4;
    const int swz = ln15 & 7;
    const int mbase = blockIdx.x * 64;

    // ---- stage A panels (64 rows x 128 cols each source), swizzled ----
    #pragma unroll
    for (int j = 0; j < 4; ++j) {
        const int idx = w * 4 + j;
        const int kt = idx >> 3, ib = idx & 7;
        const int r = ib * 8 + (lane >> 3);
        int grow = mbase + r; if (grow > NN - 1) grow = NN - 1;
        const int slot = ((lane & 7) ^ (lane >> 3)) << 3;
        const size_t goff = (size_t)grow * 128 + kt * 64 + slot;
        const int loff = kt * 4096 + ib * 512;
        gload_lds16(hb + goff, &lds[loff]);
        if (L == 1) {
            gload_lds16(xb + goff, &lds[8192 + loff]);
            gload_lds16(incb + goff, &lds[16384 + loff]);
        } else {
            gload_lds16(incb + goff, &lds[8192 + loff]);
        }
    }
    __syncthreads();

    const int K = L ? 256 : 128;
    // ---- gx GEMM ----
    f32x4 acc[4][6];
    #pragma unroll
    for (int mt = 0; mt < 4; ++mt)
        #pragma unroll
        for (int nt = 0; nt < 6; ++nt) acc[mt][nt] = (f32x4){0.f, 0.f, 0.f, 0.f};
    const int nkt = L ? 4 : 2;
    #pragma unroll
    for (int kt = 0; kt < nkt; ++kt) {
        const unsigned short* ldsA = (L == 1)
            ? ((kt < 2) ? &lds[8192 + kt * 4096] : &lds[16384 + (kt - 2) * 4096])
            : &lds[8192 + kt * 4096];
        #pragma unroll
        for (int kk = 0; kk < 2; ++kk) {
            bfrag8 aF[4], bF[6];
            #pragma unroll
            for (int mt = 0; mt < 4; ++mt)
                aF[mt] = *(const bfrag8*)&ldsA[(mt * 16 + ln15) * 64 +
                                               (((kk * 4 + quad) ^ swz) << 3)];
            #pragma unroll
            for (int nt = 0; nt < 6; ++nt)
                bF[nt] = *(const bfrag8*)&WihP[(size_t)(w * 96 + nt * 16 + ln15) * K +
                                               kt * 64 + kk * 32 + quad * 8];
            #pragma unroll
            for (int mt = 0; mt < 4; ++mt)
                #pragma unroll
                for (int nt = 0; nt < 6; ++nt)
                    acc[mt][nt] = __builtin_amdgcn_mfma_f32_16x16x32_bf16(
                        aF[mt], bF[nt], acc[mt][nt], 0, 0, 0);
        }
    }
    // bias + pack gx to bf16 pairs (frees acc for gh)
    unsigned int gxp[4][6][2];
    #pragma unroll
    for (int nt = 0; nt < 6; ++nt) {
        const float bi = bih[w * 96 + nt * 16 + ln15];
        #pragma unroll
        for (int mt = 0; mt < 4; ++mt) {
            const float v0 = acc[mt][nt][0] + bi, v1 = acc[mt][nt][1] + bi;
            const float v2 = acc[mt][nt][2] + bi, v3 = acc[mt][nt][3] + bi;
            gxp[mt][nt][0] = ((unsigned int)f2b(v1) << 16) | f2b(v0);
            gxp[mt][nt][1] = ((unsigned int)f2b(v3) << 16) | f2b(v2);
        }
    }
    // ---- gh GEMM (reuse acc) ----
    #pragma unroll
    for (int mt = 0; mt < 4; ++mt)
        #pragma unroll
        for (int nt = 0; nt < 6; ++nt) acc[mt][nt] = (f32x4){0.f, 0.f, 0.f, 0.f};
    #pragma unroll
    for (int kt = 0; kt < 2; ++kt) {
        #pragma unroll
        for (int kk = 0; kk < 2; ++kk) {
            bfrag8 aF[4], bF[6];
            #pragma unroll
            for (int mt = 0; mt < 4; ++mt)
                aF[mt] = *(const bfrag8*)&lds[kt * 4096 + (mt * 16 + ln15) * 64 +
                                              (((kk * 4 + quad) ^ swz) << 3)];
            #pragma unroll
            for (int nt = 0; nt < 6; ++nt)
                bF[nt] = *(const bfrag8*)&WhhP[(size_t)(w * 96 + nt * 16 + ln15) * 128 +
                                               kt * 64 + kk * 32 + quad * 8];
            #pragma unroll
            for (int mt = 0; mt < 4; ++mt)
                #pragma unroll
                for (int nt = 0; nt < 6; ++nt)
                    acc[mt][nt] = __builtin_amdgcn_mfma_f32_16x16x32_bf16(
                        aF[mt], bF[nt], acc[mt][nt], 0, 0, 0);
        }
    }

    // ---- GRU gate epilogue ----
    #pragma unroll
    for (int g = 0; g < 2; ++g) {
        const int grp = w * 2 + g;
        const float br = bhh[grp * 48 + ln15];
        const float bz = bhh[grp * 48 + 16 + ln15];
        const float bn = bhh[grp * 48 + 32 + ln15];
        const int col = grp * 16 + ln15;
        #pragma unroll
        for (int mt = 0; mt < 4; ++mt)
            #pragma unroll
            for (int reg = 0; reg < 4; ++reg) {
                const int row = mbase + mt * 16 + quad * 4 + reg;
                if (row < NN) {
                    const int hw = reg >> 1, sh = (reg & 1) * 16;
                    const float xr = b2f((unsigned short)(gxp[mt][g * 3 + 0][hw] >> sh));
                    const float xz = b2f((unsigned short)(gxp[mt][g * 3 + 1][hw] >> sh));
                    const float xn = b2f((unsigned short)(gxp[mt][g * 3 + 2][hw] >> sh));
                    const float hr = acc[mt][g * 3 + 0][reg] + br;
                    const float hz = acc[mt][g * 3 + 1][reg] + bz;
                    const float hn = acc[mt][g * 3 + 2][reg] + bn;
                    const float h = hcur[(size_t)row * 128 + col];
                    const float o = gru_elem(xr, xz, xn, hr, hz, hn, h);
                    hnext[(size_t)row * 128 + col] = o;
                    hbn[(size_t)row * 128 + col] = f2b(o);
                }
            }
    }
}

extern "C" void kernel_launch(void* const* d_in, const int* in_sizes, int n_in,
                              void* d_out, int out_size, void* d_ws, size_t ws_size,
                              hipStream_t stream) {
    (void)in_sizes; (void)n_in; (void)out_size; (void)ws_size;
    const float* x     = (const float*)d_in[0];
    const int*   edges = (const int*)d_in[1];
    const float* msg_W = (const float*)d_in[2];
    const float* msg_b = (const float*)d_in[3];
    const float* W0ih  = (const float*)d_in[4];
    const float* W0hh  = (const float*)d_in[5];
    const float* b0ih  = (const float*)d_in[6];
    const float* b0hh  = (const float*)d_in[7];
    const float* W1ih  = (const float*)d_in[8];
    const float* W1hh  = (const float*)d_in[9];
    const float* b1ih  = (const float*)d_in[10];
    const float* b1hh  = (const float*)d_in[11];
    float* out = (float*)d_out;

    // ---- workspace layout (float units) ----
    float* ws = (float*)d_ws;
    unsigned short* Zb   = (unsigned short*)ws;                  // N*512 u16 = 12.8M fl
    unsigned short* incb = (unsigned short*)(ws + 12800000);     // N*128 u16
    unsigned short* xb   = (unsigned short*)(ws + 16000000);     // N*128
    unsigned short* hbA  = (unsigned short*)(ws + 19200000);
    unsigned short* hbB  = (unsigned short*)(ws + 22400000);
    float* hA            = ws + 25600000;                        // N*128 fp32
    unsigned short* wb   = (unsigned short*)(ws + 32000000);
    unsigned short* msgWb = wb;               // 131072 u16
    unsigned short* W0ihP = wb + 131072;      // 49152
    unsigned short* W0hhP = wb + 180224;      // 49152
    unsigned short* W1ihP = wb + 229376;      // 98304
    unsigned short* W1hhP = wb + 327680;      // 49152
    float* biasP        = ws + 32200000;                         // 1536 fl
    int*          base2 = (int*)(ws + 32210000);                 // NN+1
    unsigned int* rows  = (unsigned int*)(ws + 32270000);        // T*E
    // build temporaries alias Zb region (dead before z_gemm writes Zb)
    int* deg2      = (int*)ws;
    int* locscan   = deg2 + NN;
    int* cursor    = deg2 + 2 * NN;
    int* blocksum  = deg2 + 3 * NN;
    int* blockpref = deg2 + 3 * NN + 1024;

    // ---- CSR build ----
    const int nblk2 = (NN + 255) / 256;  // 196
    hipMemsetAsync(deg2, 0, (size_t)NN * sizeof(int), stream);
    deg2_kernel<<<(TT * EE + 255) / 256, 256, 0, stream>>>(edges, deg2);
    scan_block<<<nblk2, 256, 0, stream>>>(deg2, locscan, blocksum, NN);
    scan_partials<<<1, 1024, 0, stream>>>(blocksum, blockpref, nblk2);
    fill_base<<<nblk2, 256, 0, stream>>>(deg2, locscan, blockpref, base2, cursor, NN);
    place2_kernel<<<(TT * EE + 255) / 256, 256, 0, stream>>>(edges, base2, cursor, rows);

    // ---- fused converts (also writes out = x as fp32 h0) ----
    setup_convert<<<26478, 256, 0, stream>>>(msg_W, W0ih, W0hh, W1ih, W1hh,
                                             b0ih, b0hh, b1ih, b1hh, x,
                                             msgWb, W0ihP, W0hhP, W1ihP, W1hhP,
                                             biasP, xb, hbA, out);

    const int mblocks = (NN + 127) / 128;   // 391
    const int gblocks = (NN + 63) / 64;     // 782
    for (int s = 0; s < 6; ++s) {
        const int l = s / 3;
        const float* hcur  = (s % 2 == 0) ? out : hA;
        float*       hnext = (s % 2 == 0) ? hA : out;
        unsigned short* hbc = (s % 2 == 0) ? hbA : hbB;
        unsigned short* hbn = (s % 2 == 0) ? hbB : hbA;

        z_gemm<<<dim3(mblocks, 4), 256, 0, stream>>>(
            hbc, msgWb + (size_t)l * 65536, msg_b + (size_t)l * 512, Zb);
        gather2<<<(NN * 16) / 256, 256, 0, stream>>>(base2, rows, Zb, incb);
        if (l == 0) {
            gxhgate<0><<<gblocks, 256, 0, stream>>>(
                hbc, xb, incb, W0ihP, biasP, W0hhP, biasP + 384,
                hcur, hnext, hbn);
        } else {
            gxhgate<1><<<gblocks, 256, 0, stream>>>(
                hbc, xb, incb, W1ihP, biasP + 768, W1hhP, biasP + 1152,
                hcur, hnext, hbn);
        }
    }
    // s=5 (odd) writes hnext=out — final h lands in d_out.
}

// Round 7
// 767.478 us; speedup vs baseline: 2.4861x; 1.2341x over previous
//
#include <hip/hip_runtime.h>
#include <cstddef>

#define NN 50000
#define HH 128
#define TT 4
#define EE 150000

typedef __attribute__((ext_vector_type(8))) short bfrag8;
typedef __attribute__((ext_vector_type(4))) float f32x4;
typedef __attribute__((ext_vector_type(8))) unsigned short u16x8;

__device__ __forceinline__ float sigm(float v) { return 1.0f / (1.0f + __expf(-v)); }

__device__ __forceinline__ float gru_elem(float xr, float xz, float xn,
                                          float hr, float hz, float hn, float h) {
    float r = sigm(xr + hr);
    float z = sigm(xz + hz);
    float nn = tanhf(xn + r * hn);
    return (1.f - z) * nn + z * h;
}

__device__ __forceinline__ unsigned short f2b(float f) {
    unsigned int u = __float_as_uint(f);
    u += 0x7fffu + ((u >> 16) & 1u);
    return (unsigned short)(u >> 16);
}
__device__ __forceinline__ float b2f(unsigned short s) {
    return __uint_as_float(((unsigned int)s) << 16);
}

__device__ __forceinline__ void gload_lds16(const void* gp, void* lp) {
    __builtin_amdgcn_global_load_lds(
        (const __attribute__((address_space(1))) unsigned int*)gp,
        (__attribute__((address_space(3))) unsigned int*)lp, 16, 0, 0);
}

// ================= CSR build (once per call) =================
__global__ __launch_bounds__(256)
void deg2_kernel(const int* __restrict__ edges, int* __restrict__ deg) {
    int eg = blockIdx.x * 256 + threadIdx.x;
    if (eg >= TT * EE) return;
    atomicAdd(&deg[edges[eg * 2 + 1]], 1);
}

__global__ __launch_bounds__(256)
void scan_block(const int* __restrict__ d, int* __restrict__ loc,
                int* __restrict__ bsum, int n) {
    __shared__ int sh[256];
    const int tid = threadIdx.x;
    const int i = blockIdx.x * 256 + tid;
    int v = (i < n) ? d[i] : 0;
    sh[tid] = v;
    __syncthreads();
    #pragma unroll
    for (int off = 1; off < 256; off <<= 1) {
        int t = (tid >= off) ? sh[tid - off] : 0;
        __syncthreads();
        sh[tid] += t;
        __syncthreads();
    }
    if (i < n) loc[i] = sh[tid];
    if (tid == 255) bsum[blockIdx.x] = sh[255];
}

__global__ __launch_bounds__(1024)
void scan_partials(const int* __restrict__ bsum, int* __restrict__ bpref, int nblk) {
    __shared__ int sh[1024];
    const int tid = threadIdx.x;
    sh[tid] = (tid < nblk) ? bsum[tid] : 0;
    __syncthreads();
    #pragma unroll
    for (int off = 1; off < 1024; off <<= 1) {
        int t = (tid >= off) ? sh[tid - off] : 0;
        __syncthreads();
        sh[tid] += t;
        __syncthreads();
    }
    if (tid < nblk) bpref[tid] = (tid == 0) ? 0 : sh[tid - 1];
}

__global__ __launch_bounds__(256)
void fill_base(const int* __restrict__ d, const int* __restrict__ loc,
               const int* __restrict__ bpref, int* __restrict__ base,
               int* __restrict__ cursor, int n) {
    const int i = blockIdx.x * 256 + threadIdx.x;
    if (i >= n) return;
    const int incl = loc[i] + bpref[blockIdx.x];
    base[i] = incl - d[i];
    cursor[i] = 0;
    if (i == n - 1) base[n] = incl;
}

__global__ __launch_bounds__(256)
void place2_kernel(const int* __restrict__ edges, const int* __restrict__ base,
                   int* __restrict__ cursor, unsigned int* __restrict__ rows) {
    int eg = blockIdx.x * 256 + threadIdx.x;
    if (eg >= TT * EE) return;
    int t = eg / EE;
    int src = edges[eg * 2];
    int tgt = edges[eg * 2 + 1];
    int p = base[tgt] + atomicAdd(&cursor[tgt], 1);
    rows[p] = (unsigned int)src * 512u + (unsigned int)t * 128u;
}

// ================= fused setup converts =================
__device__ __forceinline__ int permrow(int f) {
    int gc = f & 127, ch = f >> 7;
    return (gc >> 4) * 48 + ch * 16 + (gc & 15);
}

__global__ __launch_bounds__(256)
void setup_convert(const float* __restrict__ msg_W,
                   const float* __restrict__ W0ih, const float* __restrict__ W0hh,
                   const float* __restrict__ W1ih, const float* __restrict__ W1hh,
                   const float* __restrict__ b0ih, const float* __restrict__ b0hh,
                   const float* __restrict__ b1ih, const float* __restrict__ b1hh,
                   const float* __restrict__ x,
                   unsigned short* __restrict__ msgWb,
                   unsigned short* __restrict__ W0ihP, unsigned short* __restrict__ W0hhP,
                   unsigned short* __restrict__ W1ihP, unsigned short* __restrict__ W1hhP,
                   float* __restrict__ biasP,
                   unsigned short* __restrict__ xb, unsigned short* __restrict__ hbA,
                   float* __restrict__ out) {
    int i = blockIdx.x * 256 + threadIdx.x;
    if (i < 131072) { msgWb[i] = f2b(msg_W[i]); return; }
    i -= 131072;
    if (i < 49152) { int f = i >> 7, k = i & 127; W0ihP[permrow(f) * 128 + k] = f2b(W0ih[i]); return; }
    i -= 49152;
    if (i < 49152) { int f = i >> 7, k = i & 127; W0hhP[permrow(f) * 128 + k] = f2b(W0hh[i]); return; }
    i -= 49152;
    if (i < 98304) { int f = i >> 8, k = i & 255; W1ihP[permrow(f) * 256 + k] = f2b(W1ih[i]); return; }
    i -= 98304;
    if (i < 49152) { int f = i >> 7, k = i & 127; W1hhP[permrow(f) * 128 + k] = f2b(W1hh[i]); return; }
    i -= 49152;
    if (i < 1536) {
        int which = i / 384, f = i - which * 384;
        const float* src = (which == 0) ? b0ih : (which == 1) ? b0hh : (which == 2) ? b1ih : b1hh;
        biasP[which * 384 + permrow(f)] = src[f];
        return;
    }
    i -= 1536;
    if (i < NN * HH) {
        float v = x[i];
        unsigned short b = f2b(v);
        xb[i] = b;
        hbA[i] = b;
        out[i] = v;
    }
}

// ================= gather: inc[n] = sum_edges Z[rows[p] + c] =================
// 32 lanes per node: 2 edge-halves x 16 col-lanes; shuffle-combine. grid exact NN*32/256.
__global__ __launch_bounds__(256)
void gather2(const int* __restrict__ base, const unsigned int* __restrict__ rows,
             const unsigned short* __restrict__ Z, unsigned short* __restrict__ incb) {
    int gid = blockIdx.x * 256 + threadIdx.x;
    int n = gid >> 5;
    int sub = (gid >> 4) & 1;
    int c = (gid & 15) * 8;
    const int p0 = base[n];
    const int p1 = base[n + 1];
    float a[8] = {};
    int p = p0 + sub;
    for (; p + 6 < p1; p += 8) {
        unsigned int o0 = rows[p], o1 = rows[p + 2], o2 = rows[p + 4], o3 = rows[p + 6];
        u16x8 v0 = *(const u16x8*)&Z[o0 + c];
        u16x8 v1 = *(const u16x8*)&Z[o1 + c];
        u16x8 v2 = *(const u16x8*)&Z[o2 + c];
        u16x8 v3 = *(const u16x8*)&Z[o3 + c];
        #pragma unroll
        for (int j = 0; j < 8; ++j)
            a[j] += (b2f((unsigned short)v0[j]) + b2f((unsigned short)v1[j]))
                  + (b2f((unsigned short)v2[j]) + b2f((unsigned short)v3[j]));
    }
    for (; p < p1; p += 2) {
        u16x8 v = *(const u16x8*)&Z[rows[p] + c];
        #pragma unroll
        for (int j = 0; j < 8; ++j) a[j] += b2f((unsigned short)v[j]);
    }
    #pragma unroll
    for (int j = 0; j < 8; ++j) a[j] += __shfl_xor(a[j], 16, 64);
    if (sub == 0) {
        u16x8 o;
        #pragma unroll
        for (int j = 0; j < 8; ++j) o[j] = f2b(a[j]);
        *(u16x8*)&incb[(size_t)n * 128 + c] = o;
    }
}

// ================= Z GEMM: Z = h @ msgW^T + msg_b (128x128 tile) =================
__global__ __launch_bounds__(256)
void z_gemm(const unsigned short* __restrict__ A0,
            const unsigned short* __restrict__ B,
            const float* __restrict__ bias,
            unsigned short* __restrict__ C) {
    __shared__ unsigned short lsA[128 * 64];
    __shared__ unsigned short lsB[128 * 64];
    const int tid = threadIdx.x;
    const int lane = tid & 63;
    const int w = tid >> 6;
    const int wm = w >> 1, wn = w & 1;
    const int ln15 = lane & 15;
    const int quad = lane >> 4;
    const int swz = ln15 & 7;
    const int mbase = blockIdx.x * 128;
    const int fbase = blockIdx.y * 128;
    const int qg = (lane & 7) ^ (lane >> 3);

    f32x4 acc[4][4];
    #pragma unroll
    for (int i = 0; i < 4; ++i)
        #pragma unroll
        for (int j = 0; j < 4; ++j)
            acc[i][j] = (f32x4){0.f, 0.f, 0.f, 0.f};

    #pragma unroll
    for (int tile = 0; tile < 2; ++tile) {
        const int ck0 = tile << 3;
        #pragma unroll
        for (int i = 0; i < 4; ++i) {
            const int r = i * 32 + (w << 3) + (lane >> 3);
            const int chunk = ck0 + qg;
            int grow = mbase + r;
            if (grow > NN - 1) grow = NN - 1;
            const int kel = chunk << 3;
            gload_lds16(A0 + (size_t)grow * 128 + kel, &lsA[(i * 32 + (w << 3)) * 64]);
            gload_lds16(B + (size_t)(fbase + r) * 128 + kel, &lsB[(i * 32 + (w << 3)) * 64]);
        }
        __syncthreads();
        #pragma unroll
        for (int kk = 0; kk < 2; ++kk) {
            const int cs = (((kk * 4 + quad) ^ swz)) << 3;
            bfrag8 aF[4], bF[4];
            #pragma unroll
            for (int mt = 0; mt < 4; ++mt)
                aF[mt] = *(const bfrag8*)&lsA[(wm * 64 + mt * 16 + ln15) * 64 + cs];
            #pragma unroll
            for (int nt = 0; nt < 4; ++nt)
                bF[nt] = *(const bfrag8*)&lsB[(wn * 64 + nt * 16 + ln15) * 64 + cs];
            #pragma unroll
            for (int mt = 0; mt < 4; ++mt)
                #pragma unroll
                for (int nt = 0; nt < 4; ++nt)
                    acc[mt][nt] = __builtin_amdgcn_mfma_f32_16x16x32_bf16(
                        aF[mt], bF[nt], acc[mt][nt], 0, 0, 0);
        }
        __syncthreads();
    }

    float bcol[4];
    #pragma unroll
    for (int nt = 0; nt < 4; ++nt)
        bcol[nt] = bias[fbase + wn * 64 + nt * 16 + ln15];
    #pragma unroll
    for (int mt = 0; mt < 4; ++mt) {
        #pragma unroll
        for (int reg = 0; reg < 4; ++reg) {
            const int grow = mbase + wm * 64 + mt * 16 + quad * 4 + reg;
            if (grow < NN) {
                #pragma unroll
                for (int nt = 0; nt < 4; ++nt) {
                    const int gcol = fbase + wn * 64 + nt * 16 + ln15;
                    C[(size_t)grow * 512 + gcol] = f2b(acc[mt][nt][reg] + bcol[nt]);
                }
            }
        }
    }
}

// ========== generic gx GEMM: C = [A0|A1] @ B^T + bias (B LDS-staged) ==========
__global__ __launch_bounds__(256)
void mfma_gemm(const unsigned short* __restrict__ A0,
               const unsigned short* __restrict__ A1, int K0, int K,
               const unsigned short* __restrict__ B,
               const float* __restrict__ bias,
               unsigned short* __restrict__ C, int ldc, int M) {
    __shared__ unsigned short lsA[128 * 64];
    __shared__ unsigned short lsB[128 * 64];
    const int tid = threadIdx.x;
    const int lane = tid & 63;
    const int w = tid >> 6;
    const int wm = w >> 1, wn = w & 1;
    const int ln15 = lane & 15;
    const int quad = lane >> 4;
    const int swz = ln15 & 7;
    const int mbase = blockIdx.x * 128;
    const int fbase = blockIdx.y * 128;
    const int qg = (lane & 7) ^ (lane >> 3);

    f32x4 acc[4][4];
    #pragma unroll
    for (int i = 0; i < 4; ++i)
        #pragma unroll
        for (int j = 0; j < 4; ++j)
            acc[i][j] = (f32x4){0.f, 0.f, 0.f, 0.f};

    const int ntiles = K >> 6;
    for (int tile = 0; tile < ntiles; ++tile) {
        const int ck0 = tile << 3;
        #pragma unroll
        for (int i = 0; i < 4; ++i) {
            const int r = i * 32 + (w << 3) + (lane >> 3);
            const int chunk = ck0 + qg;
            int grow = mbase + r;
            if (grow > M - 1) grow = M - 1;
            const int kel = chunk << 3;
            const unsigned short* gpA =
                (kel < K0) ? (A0 + (size_t)grow * K0 + kel)
                           : (A1 + (size_t)grow * (K - K0) + (kel - K0));
            gload_lds16(gpA, &lsA[(i * 32 + (w << 3)) * 64]);
            gload_lds16(B + (size_t)(fbase + r) * K + kel, &lsB[(i * 32 + (w << 3)) * 64]);
        }
        __syncthreads();
        #pragma unroll
        for (int kk = 0; kk < 2; ++kk) {
            const int cs = (((kk * 4 + quad) ^ swz)) << 3;
            bfrag8 aF[4], bF[4];
            #pragma unroll
            for (int mt = 0; mt < 4; ++mt)
                aF[mt] = *(const bfrag8*)&lsA[(wm * 64 + mt * 16 + ln15) * 64 + cs];
            #pragma unroll
            for (int nt = 0; nt < 4; ++nt)
                bF[nt] = *(const bfrag8*)&lsB[(wn * 64 + nt * 16 + ln15) * 64 + cs];
            #pragma unroll
            for (int mt = 0; mt < 4; ++mt)
                #pragma unroll
                for (int nt = 0; nt < 4; ++nt)
                    acc[mt][nt] = __builtin_amdgcn_mfma_f32_16x16x32_bf16(
                        aF[mt], bF[nt], acc[mt][nt], 0, 0, 0);
        }
        __syncthreads();
    }

    float bcol[4];
    #pragma unroll
    for (int nt = 0; nt < 4; ++nt)
        bcol[nt] = bias[fbase + wn * 64 + nt * 16 + ln15];
    #pragma unroll
    for (int mt = 0; mt < 4; ++mt) {
        #pragma unroll
        for (int reg = 0; reg < 4; ++reg) {
            const int grow = mbase + wm * 64 + mt * 16 + quad * 4 + reg;
            if (grow < M) {
                #pragma unroll
                for (int nt = 0; nt < 4; ++nt) {
                    const int gcol = fbase + wn * 64 + nt * 16 + ln15;
                    C[(size_t)grow * ldc + gcol] = f2b(acc[mt][nt][reg] + bcol[nt]);
                }
            }
        }
    }
}

// ================= fused gh-GEMM + GRU gate (512 thr, B LDS-staged) =================
__global__ __launch_bounds__(512)
void ghgate_kernel(const unsigned short* __restrict__ hb,
                   const unsigned short* __restrict__ Wp,
                   const float* __restrict__ bp,
                   const unsigned short* __restrict__ gx,
                   const float* __restrict__ hcur,
                   float* __restrict__ hnext, unsigned short* __restrict__ hbn,
                   int M) {
    __shared__ unsigned short lsA[64 * 64];    // 8 KB
    __shared__ unsigned short lsB[384 * 64];   // 48 KB
    const int tid = threadIdx.x;
    const int lane = tid & 63;
    const int w = tid >> 6;             // 0..7
    const int ln15 = lane & 15;
    const int quad = lane >> 4;
    const int swz = ln15 & 7;
    const int mbase = blockIdx.x * 64;
    const int srow = tid >> 3;          // staging row 0..63
    const int slot = tid & 7;

    f32x4 acc[4][3];
    #pragma unroll
    for (int i = 0; i < 4; ++i)
        #pragma unroll
        for (int j = 0; j < 3; ++j)
            acc[i][j] = (f32x4){0.f, 0.f, 0.f, 0.f};

    #pragma unroll
    for (int tile = 0; tile < 2; ++tile) {
        const int ck0 = tile << 3;
        {
            int grow = mbase + srow;
            if (grow > M - 1) grow = M - 1;
            const int chunk = ck0 + (slot ^ (srow & 7));
            gload_lds16(hb + (size_t)grow * 128 + (chunk << 3), &lsA[tid * 8]);
        }
        #pragma unroll
        for (int pi = 0; pi < 6; ++pi) {
            const int brow = pi * 64 + srow;
            const int chunk = ck0 + (slot ^ (srow & 7));
            gload_lds16(Wp + (size_t)brow * 128 + (chunk << 3),
                        &lsB[(pi * 512 + tid) * 8]);
        }
        __syncthreads();
        #pragma unroll
        for (int kk = 0; kk < 2; ++kk) {
            const int cs = ((kk * 4 + quad) ^ swz) << 3;
            bfrag8 aF[4], bF[3];
            #pragma unroll
            for (int mt = 0; mt < 4; ++mt)
                aF[mt] = *(const bfrag8*)&lsA[(mt * 16 + ln15) * 64 + cs];
            #pragma unroll
            for (int nt = 0; nt < 3; ++nt) {
                const int rb = w * 48 + nt * 16 + ln15;
                bF[nt] = *(const bfrag8*)&lsB[rb * 64 + cs];
            }
            #pragma unroll
            for (int mt = 0; mt < 4; ++mt)
                #pragma unroll
                for (int nt = 0; nt < 3; ++nt)
                    acc[mt][nt] = __builtin_amdgcn_mfma_f32_16x16x32_bf16(
                        aF[mt], bF[nt], acc[mt][nt], 0, 0, 0);
        }
        __syncthreads();
    }

    const float br = bp[w * 48 + ln15];
    const float bz = bp[w * 48 + 16 + ln15];
    const float bn = bp[w * 48 + 32 + ln15];
    const int gc = w * 16 + ln15;
    #pragma unroll
    for (int mt = 0; mt < 4; ++mt) {
        #pragma unroll
        for (int reg = 0; reg < 4; ++reg) {
            const int row = mbase + mt * 16 + quad * 4 + reg;
            if (row < M) {
                const size_t gb = (size_t)row * 384 + w * 48;
                const float xr = b2f(gx[gb + ln15]);
                const float xz = b2f(gx[gb + 16 + ln15]);
                const float xn = b2f(gx[gb + 32 + ln15]);
                const float hrv = acc[mt][0][reg] + br;
                const float hzv = acc[mt][1][reg] + bz;
                const float hnv = acc[mt][2][reg] + bn;
                const float h = hcur[(size_t)row * 128 + gc];
                const float o = gru_elem(xr, xz, xn, hrv, hzv, hnv, h);
                hnext[(size_t)row * 128 + gc] = o;
                hbn[(size_t)row * 128 + gc] = f2b(o);
            }
        }
    }
}

extern "C" void kernel_launch(void* const* d_in, const int* in_sizes, int n_in,
                              void* d_out, int out_size, void* d_ws, size_t ws_size,
                              hipStream_t stream) {
    (void)in_sizes; (void)n_in; (void)out_size; (void)ws_size;
    const float* x     = (const float*)d_in[0];
    const int*   edges = (const int*)d_in[1];
    const float* msg_W = (const float*)d_in[2];
    const float* msg_b = (const float*)d_in[3];
    const float* W0ih  = (const float*)d_in[4];
    const float* W0hh  = (const float*)d_in[5];
    const float* b0ih  = (const float*)d_in[6];
    const float* b0hh  = (const float*)d_in[7];
    const float* W1ih  = (const float*)d_in[8];
    const float* W1hh  = (const float*)d_in[9];
    const float* b1ih  = (const float*)d_in[10];
    const float* b1hh  = (const float*)d_in[11];
    float* out = (float*)d_out;

    // ---- workspace layout (float units) ----
    float* ws = (float*)d_ws;
    unsigned short* Zb   = (unsigned short*)ws;                  // N*512 u16 = 12.8M fl
    unsigned short* gxb  = (unsigned short*)(ws + 12800000);     // N*384 u16 =  9.6M fl
    unsigned short* incb = (unsigned short*)(ws + 22400000);     // N*128 u16
    unsigned short* xb   = (unsigned short*)(ws + 25600000);     // N*128
    unsigned short* hbA  = (unsigned short*)(ws + 28800000);
    unsigned short* hbB  = (unsigned short*)(ws + 32000000);
    float* hA            = ws + 35200000;                        // N*128 fp32
    unsigned short* wb   = (unsigned short*)(ws + 41600000);
    unsigned short* msgWb = wb;               // 131072 u16
    unsigned short* W0ihP = wb + 131072;      // 49152
    unsigned short* W0hhP = wb + 180224;      // 49152
    unsigned short* W1ihP = wb + 229376;      // 98304
    unsigned short* W1hhP = wb + 327680;      // 49152
    float* biasP        = ws + 41800000;                         // 1536 fl
    int*          base2 = (int*)(ws + 41900000);                 // NN+1
    unsigned int* rows  = (unsigned int*)(ws + 42000000);        // T*E
    // build temporaries alias Zb region (dead before z_gemm writes Zb)
    int* deg2      = (int*)ws;
    int* locscan   = deg2 + NN;
    int* cursor    = deg2 + 2 * NN;
    int* blocksum  = deg2 + 3 * NN;
    int* blockpref = deg2 + 3 * NN + 1024;

    // ---- CSR build ----
    const int nblk2 = (NN + 255) / 256;  // 196
    hipMemsetAsync(deg2, 0, (size_t)NN * sizeof(int), stream);
    deg2_kernel<<<(TT * EE + 255) / 256, 256, 0, stream>>>(edges, deg2);
    scan_block<<<nblk2, 256, 0, stream>>>(deg2, locscan, blocksum, NN);
    scan_partials<<<1, 1024, 0, stream>>>(blocksum, blockpref, nblk2);
    fill_base<<<nblk2, 256, 0, stream>>>(deg2, locscan, blockpref, base2, cursor, NN);
    place2_kernel<<<(TT * EE + 255) / 256, 256, 0, stream>>>(edges, base2, cursor, rows);

    // ---- fused converts (also writes out = x as fp32 h0) ----
    setup_convert<<<26478, 256, 0, stream>>>(msg_W, W0ih, W0hh, W1ih, W1hh,
                                             b0ih, b0hh, b1ih, b1hh, x,
                                             msgWb, W0ihP, W0hhP, W1ihP, W1hhP,
                                             biasP, xb, hbA, out);

    const int mblocks = (NN + 127) / 128;   // 391
    const int gblocks = (NN + 63) / 64;     // 782
    for (int s = 0; s < 6; ++s) {
        const int l = s / 3;
        const float* hcur  = (s % 2 == 0) ? out : hA;
        float*       hnext = (s % 2 == 0) ? hA : out;
        unsigned short* hbc = (s % 2 == 0) ? hbA : hbB;
        unsigned short* hbn = (s % 2 == 0) ? hbB : hbA;

        z_gemm<<<dim3(mblocks, 4), 256, 0, stream>>>(
            hbc, msgWb + (size_t)l * 65536, msg_b + (size_t)l * 512, Zb);
        gather2<<<(NN * 32) / 256, 256, 0, stream>>>(base2, rows, Zb, incb);
        if (l == 0) {
            mfma_gemm<<<dim3(mblocks, 3), 256, 0, stream>>>(
                incb, incb, 128, 128, W0ihP, biasP, gxb, 384, NN);
            ghgate_kernel<<<gblocks, 512, 0, stream>>>(
                hbc, W0hhP, biasP + 384, gxb, hcur, hnext, hbn, NN);
        } else {
            mfma_gemm<<<dim3(mblocks, 3), 256, 0, stream>>>(
                xb, incb, 128, 256, W1ihP, biasP + 768, gxb, 384, NN);
            ghgate_kernel<<<gblocks, 512, 0, stream>>>(
                hbc, W1hhP, biasP + 1152, gxb, hcur, hnext, hbn, NN);
        }
    }
    // s=5 (odd) writes hnext=out — final h lands in d_out.
}